// Round 1
// baseline (15595.491 us; speedup 1.0000x reference)
//
#include <hip/hip_runtime.h>
#include <hip/hip_cooperative_groups.h>
#include <math.h>

namespace cg = cooperative_groups;

#define H    1024
#define B    128
#define T    256
#define NBLK 256   // grid blocks; block bk owns hidden dims [4*bk, 4*bk+4)
#define NTHR 512   // threads per block (8 waves)

__device__ __forceinline__ float sigmoidf_(float x) {
    return 1.0f / (1.0f + __expf(-x));
}

// Persistent cooperative LSTM decoder.
// Layout per block: 16 W_hh rows (4 hidden dims x 4 gates i,f,g,o) in LDS fp32.
// h double-buffered in ws; per-block OUT partials double-buffered in ws.
// c-state is block-private in LDS. One grid sync per timestep.
__global__ __launch_bounds__(NTHR, 2) void decoder_kernel(
    const float* __restrict__ hidden0, const float* __restrict__ cell0,
    const float* __restrict__ Wih,     const float* __restrict__ Whh,
    const float* __restrict__ bih,     const float* __restrict__ bhh,
    const float* __restrict__ Wlin,    const float* __restrict__ blin,
    float* __restrict__ out,           float* __restrict__ ws)
{
    __shared__ float W_s[16][H];       // 64 KB: this block's 16 W_hh rows
    __shared__ float p_s[4][B][16];    // 32 KB: k-quarter partial gates
    __shared__ float c_s[4 * B];       // 2 KB: cell state for 4 hidden dims
    __shared__ float wih0_s[16], wih1_s[16], bias_s[16], wlin_s[4];

    const int bk  = blockIdx.x;        // 0..255
    const int j0  = bk * 4;            // first owned hidden dim
    const int tid = threadIdx.x;

    float* hbuf0 = ws;                  // [B*H]
    float* hbuf1 = ws + B * H;          // [B*H]
    float* pout  = ws + 2 * B * H;      // [2][B][NBLK] double-buffered OUT partials

    // ---- preamble: stage weights, init state ----
    for (int idx = tid; idx < 16 * H; idx += NTHR) {
        int rl = idx >> 10, k = idx & (H - 1);
        int gate = rl >> 2, jj = rl & 3;
        W_s[rl][k] = Whh[(gate * H + j0 + jj) * H + k];
    }
    if (tid < 16) {
        int gate = tid >> 2, jj = tid & 3;
        int grow = gate * H + j0 + jj;
        wih0_s[tid] = Wih[grow * 2 + 0];
        wih1_s[tid] = Wih[grow * 2 + 1];
        bias_s[tid] = bih[grow] + bhh[grow];
    }
    if (tid < 4) wlin_s[tid] = Wlin[j0 + tid];
    if (tid < B) {
        int b = tid;
        #pragma unroll
        for (int jj = 0; jj < 4; ++jj)
            c_s[jj * B + b] = cell0[b * H + j0 + jj];
        // each block seeds its own 4 columns of h_0
        float4 hv = *(const float4*)(hidden0 + b * H + j0);
        *(float4*)(hbuf0 + b * H + j0) = hv;
    }
    cg::this_grid().sync();

    const float bl = blin[0];
    float out_prev = 0.0f;

    for (int t = 0; t < T; ++t) {
        const float* hcur = (t & 1) ? hbuf1 : hbuf0;
        float*       hnxt = (t & 1) ? hbuf0 : hbuf1;
        float*       pwr  = pout + (t & 1) * B * NBLK;        // written this step
        const float* prd  = pout + ((t + 1) & 1) * B * NBLK;  // written at t-1

        // ---- reduce OUT partials from previous step (feedback input) ----
        if (t > 0 && tid < B) {
            const float4* pr = (const float4*)(prd + tid * NBLK);
            float s = 0.0f;
            #pragma unroll 8
            for (int i = 0; i < NBLK / 4; ++i) {
                float4 v = pr[i];
                s += v.x + v.y + v.z + v.w;
            }
            out_prev = bl + s;
            if (bk == 0) out[tid * T + (t - 1)] = out_prev;   // (B,T) layout
        }

        // ---- GEMM: p_s[kq][b][r] = sum_k h[b][k] * W_s[r][k] over k-quarter ----
        {
            const int b  = tid & (B - 1);
            const int kq = tid >> 7;   // 0..3
            const float* hrow  = hcur + b * H + kq * 256;
            const float* wbase = &W_s[0][kq * 256];
            float acc[16];
            #pragma unroll
            for (int r = 0; r < 16; ++r) acc[r] = 0.0f;
            for (int kk = 0; kk < 256; kk += 4) {
                float4 hv = *(const float4*)(hrow + kk);
                #pragma unroll
                for (int r = 0; r < 16; ++r) {
                    float4 wv = *(const float4*)(wbase + r * H + kk);
                    acc[r] = fmaf(hv.x, wv.x, acc[r]);
                    acc[r] = fmaf(hv.y, wv.y, acc[r]);
                    acc[r] = fmaf(hv.z, wv.z, acc[r]);
                    acc[r] = fmaf(hv.w, wv.w, acc[r]);
                }
            }
            #pragma unroll
            for (int r = 0; r < 16; ++r) p_s[kq][b][r] = acc[r];
        }
        __syncthreads();

        // ---- LSTM pointwise + OUT-head partial (threads 0..127 = batch) ----
        if (tid < B) {
            const int b = tid;
            float g[16];
            #pragma unroll
            for (int r = 0; r < 16; ++r)
                g[r] = p_s[0][b][r] + p_s[1][b][r] + p_s[2][b][r] + p_s[3][b][r]
                     + bias_s[r];
            if (t > 0) {   // t==0: inp = [0, 0] -> no W_ih contribution
                #pragma unroll
                for (int r = 0; r < 16; ++r)
                    g[r] += wih0_s[r] * out_prev + wih1_s[r];
            }
            float hn[4];
            float po = 0.0f;
            #pragma unroll
            for (int jj = 0; jj < 4; ++jj) {
                float ig = sigmoidf_(g[jj]);        // i
                float fg = sigmoidf_(g[4 + jj]);    // f
                float gg = tanhf(g[8 + jj]);        // g
                float og = sigmoidf_(g[12 + jj]);   // o
                float cc = fg * c_s[jj * B + b] + ig * gg;
                c_s[jj * B + b] = cc;
                float hh = og * tanhf(cc);
                hn[jj] = hh;
                po += hh * wlin_s[jj];
            }
            *(float4*)(hnxt + b * H + j0) = make_float4(hn[0], hn[1], hn[2], hn[3]);
            pwr[b * NBLK + bk] = po;
        }
        cg::this_grid().sync();
    }

    // ---- final output column t = T-1 ----
    if (bk == 0 && tid < B) {
        const float* pr = pout + ((T - 1) & 1) * B * NBLK + tid * NBLK;
        float s = 0.0f;
        for (int i = 0; i < NBLK; ++i) s += pr[i];
        out[tid * T + (T - 1)] = bl + s;
    }
}

extern "C" void kernel_launch(void* const* d_in, const int* in_sizes, int n_in,
                              void* d_out, int out_size, void* d_ws, size_t ws_size,
                              hipStream_t stream) {
    const float* hidden0 = (const float*)d_in[0];
    const float* cell0   = (const float*)d_in[1];
    const float* Wih     = (const float*)d_in[2];
    const float* Whh     = (const float*)d_in[3];
    const float* bih     = (const float*)d_in[4];
    const float* bhh     = (const float*)d_in[5];
    const float* Wlin    = (const float*)d_in[6];
    const float* blin    = (const float*)d_in[7];
    float* out = (float*)d_out;
    float* ws  = (float*)d_ws;

    void* args[] = { &hidden0, &cell0, &Wih, &Whh, &bih, &bhh, &Wlin, &blin,
                     &out, &ws };
    hipLaunchCooperativeKernel((const void*)decoder_kernel,
                               dim3(NBLK), dim3(NTHR), args, 0, stream);
}

// Round 2
// 7395.161 us; speedup vs baseline: 2.1089x; 2.1089x over previous
//
#include <hip/hip_runtime.h>
#include <math.h>

#define H     1024
#define B     128
#define T     256
#define GROUPS 4
#define BPG   64        // blocks per group (each owns 16 hidden dims)
#define NTHR  512
#define MPG   32        // batches per group
#define KPAD  1032      // padded LDS row stride in bf16 elems (breaks 16-way conflict)

typedef __attribute__((ext_vector_type(8))) short  bf16x8;
typedef __attribute__((ext_vector_type(4))) float  floatx4;

__device__ __forceinline__ unsigned short bf16_rne(float f) {
    unsigned int u = __float_as_uint(f);
    u += 0x7FFF + ((u >> 16) & 1);
    return (unsigned short)(u >> 16);
}
__device__ __forceinline__ float bf16_to_f(unsigned short h) {
    return __uint_as_float(((unsigned int)h) << 16);
}
__device__ __forceinline__ float sigmoidf_(float x) { return 1.0f / (1.0f + __expf(-x)); }

// Persistent LSTM decoder. 4 independent groups of 64 blocks; group g owns
// batches [32g,32g+32). Block rb owns hidden dims [16rb,16rb+16) => 64 gate
// rows. W' = W_hh + W_ih[:,0] (x) W_lin lives in registers as split-bf16
// MFMA B-fragments (wave = (gate, K-half), no duplication, 128 VGPR/lane).
// One 64-block flag barrier per timestep; h fp32 double-buffered in ws.
__global__ __launch_bounds__(NTHR, 2) void decoder_kernel(
    const float* __restrict__ hidden0, const float* __restrict__ cell0,
    const float* __restrict__ Wih,     const float* __restrict__ Whh,
    const float* __restrict__ bih,     const float* __restrict__ bhh,
    const float* __restrict__ Wlin,    const float* __restrict__ blin,
    float* __restrict__ out,           float* __restrict__ ws)
{
    __shared__ unsigned short lds_hi[MPG * KPAD];   // 64.5 KB  h_t hi-bf16
    __shared__ unsigned short lds_lo[MPG * KPAD];   // 64.5 KB  h_t lo-bf16
    __shared__ float Dlds[4][2][MPG][16];           // 16 KB    gate partials
    __shared__ float s0_lds[MPG];

    const int blk  = blockIdx.x;
    const int g    = blk >> 6;          // group 0..3
    const int rb   = blk & 63;          // block in group
    const int tid  = threadIdx.x;
    const int lane = tid & 63;
    const int wave = tid >> 6;          // 8 waves: (gate, kh)
    const int gate = wave & 3;
    const int kh   = wave >> 2;
    const int l15  = lane & 15;         // = n for B-frag / m for A-frag
    const int q    = lane >> 4;

    unsigned int* arrive  = (unsigned int*)ws + g * 64;        // zeroed by memset
    unsigned int* release = (unsigned int*)ws + 256 + g * 32;  // zeroed by memset
    float* hbufs = (float*)ws + 1024;                          // 2 x [B][H] fp32

    // ---- build W' B-fragments in registers (split hi/lo bf16) ----
    const int row = gate * H + rb * 16 + l15;      // this lane's gate row
    bf16x8 w_hi[16], w_lo[16];
    {
        const float* wrow  = Whh + (size_t)row * H;
        const float  wih0r = Wih[row * 2];
        #pragma unroll
        for (int kt = 0; kt < 16; ++kt) {
            const int k0 = kh * 512 + kt * 32 + q * 8;
            #pragma unroll
            for (int j = 0; j < 8; ++j) {
                float w = wrow[k0 + j] + wih0r * Wlin[k0 + j];
                unsigned short hs = bf16_rne(w);
                float lo = w - bf16_to_f(hs);
                w_hi[kt][j] = (short)hs;
                w_lo[kt][j] = (short)bf16_rne(lo);
            }
        }
    }

    // ---- pointwise-thread constants: thread (pm, pj) ----
    const int pm    = tid >> 4;               // batch in group 0..31
    const int pj    = tid & 15;               // dim within block 0..15
    const int bglob = g * MPG + pm;
    const int Jglob = rb * 16 + pj;
    const float bl  = blin[0];
    float bias_p[4], bias0_p[4], wih0_p[4];
    #pragma unroll
    for (int gt = 0; gt < 4; ++gt) {
        int r2 = gt * H + Jglob;
        float b0 = bih[r2] + bhh[r2];
        float w0 = Wih[r2 * 2];
        bias0_p[gt] = b0;
        wih0_p[gt]  = w0;
        bias_p[gt]  = b0 + Wih[r2 * 2 + 1] + w0 * bl;   // folded bias (t>=1)
    }
    float cstate = cell0[(size_t)bglob * H + Jglob];
    const float wlin_p = Wlin[Jglob];

    // ---- s0[m] = Wlin . h0[m]  (t=0 rank-1 correction) ----
    {
        const float* hp = hidden0 + (size_t)bglob * H + pj * 64;
        const float* wp = Wlin + pj * 64;
        float s = 0.f;
        #pragma unroll 4
        for (int kk = 0; kk < 64; kk += 4) {
            float4 hv = *(const float4*)(hp + kk);
            float4 wv = *(const float4*)(wp + kk);
            s += hv.x * wv.x + hv.y * wv.y + hv.z * wv.z + hv.w * wv.w;
        }
        s += __shfl_xor(s, 1); s += __shfl_xor(s, 2);
        s += __shfl_xor(s, 4); s += __shfl_xor(s, 8);
        if (pj == 0) s0_lds[pm] = s;
    }

    for (int t = 0; t < T; ++t) {
        // ---- stage h_t (fp32) -> LDS hi/lo bf16 planes ----
        const float* hsrc = (t == 0)
            ? (hidden0 + (size_t)g * MPG * H)
            : (hbufs + (size_t)(t & 1) * B * H + (size_t)g * MPG * H);
        #pragma unroll 4
        for (int s = 0; s < 16; ++s) {
            int fi = (s * NTHR + tid) * 4;            // 32*1024 floats total
            float4 v = *(const float4*)(hsrc + fi);
            int m = fi >> 10, k = fi & 1023;
            ushort4 hh, ll;
            hh.x = bf16_rne(v.x); ll.x = bf16_rne(v.x - bf16_to_f(hh.x));
            hh.y = bf16_rne(v.y); ll.y = bf16_rne(v.y - bf16_to_f(hh.y));
            hh.z = bf16_rne(v.z); ll.z = bf16_rne(v.z - bf16_to_f(hh.z));
            hh.w = bf16_rne(v.w); ll.w = bf16_rne(v.w - bf16_to_f(hh.w));
            *(ushort4*)&lds_hi[m * KPAD + k] = hh;
            *(ushort4*)&lds_lo[m * KPAD + k] = ll;
        }
        __syncthreads();

        // ---- MFMA: D[m][n] = sum_k h[m][k] W'[n][k], K-half kh ----
        floatx4 acc0 = {0.f, 0.f, 0.f, 0.f};
        floatx4 acc1 = {0.f, 0.f, 0.f, 0.f};
        const int kb = kh * 512;
        #pragma unroll
        for (int kt = 0; kt < 16; ++kt) {
            const int ko = kb + kt * 32 + q * 8;
            bf16x8 a0h = *(const bf16x8*)&lds_hi[l15 * KPAD + ko];
            bf16x8 a0l = *(const bf16x8*)&lds_lo[l15 * KPAD + ko];
            acc0 = __builtin_amdgcn_mfma_f32_16x16x32_bf16(a0h, w_hi[kt], acc0, 0, 0, 0);
            acc0 = __builtin_amdgcn_mfma_f32_16x16x32_bf16(a0l, w_hi[kt], acc0, 0, 0, 0);
            acc0 = __builtin_amdgcn_mfma_f32_16x16x32_bf16(a0h, w_lo[kt], acc0, 0, 0, 0);
            bf16x8 a1h = *(const bf16x8*)&lds_hi[(16 + l15) * KPAD + ko];
            bf16x8 a1l = *(const bf16x8*)&lds_lo[(16 + l15) * KPAD + ko];
            acc1 = __builtin_amdgcn_mfma_f32_16x16x32_bf16(a1h, w_hi[kt], acc1, 0, 0, 0);
            acc1 = __builtin_amdgcn_mfma_f32_16x16x32_bf16(a1l, w_hi[kt], acc1, 0, 0, 0);
            acc1 = __builtin_amdgcn_mfma_f32_16x16x32_bf16(a1h, w_lo[kt], acc1, 0, 0, 0);
        }
        #pragma unroll
        for (int r = 0; r < 4; ++r) {      // C/D: col=lane&15, row=q*4+r
            Dlds[gate][kh][q * 4 + r][l15]      = acc0[r];
            Dlds[gate][kh][16 + q * 4 + r][l15] = acc1[r];
        }
        __syncthreads();

        // ---- LSTM pointwise (all 512 threads: (pm, pj)) ----
        {
            float gi = Dlds[0][0][pm][pj] + Dlds[0][1][pm][pj];
            float gf = Dlds[1][0][pm][pj] + Dlds[1][1][pm][pj];
            float gg = Dlds[2][0][pm][pj] + Dlds[2][1][pm][pj];
            float go = Dlds[3][0][pm][pj] + Dlds[3][1][pm][pj];
            if (t == 0) {
                float s0 = s0_lds[pm];
                gi += bias0_p[0] - wih0_p[0] * s0;
                gf += bias0_p[1] - wih0_p[1] * s0;
                gg += bias0_p[2] - wih0_p[2] * s0;
                go += bias0_p[3] - wih0_p[3] * s0;
            } else {
                gi += bias_p[0]; gf += bias_p[1];
                gg += bias_p[2]; go += bias_p[3];
            }
            float ig = sigmoidf_(gi);
            float fg = sigmoidf_(gf);
            float gt_ = tanhf(gg);
            float og = sigmoidf_(go);
            cstate = fg * cstate + ig * gt_;
            float hnew = og * tanhf(cstate);
            hbufs[(size_t)((t + 1) & 1) * B * H + (size_t)bglob * H + Jglob] = hnew;
            // out_t[b] partial over this block's 16 dims
            float po = wlin_p * hnew;
            po += __shfl_xor(po, 1); po += __shfl_xor(po, 2);
            po += __shfl_xor(po, 4); po += __shfl_xor(po, 8);
            if (pj == 0)
                atomicAdd(&out[(size_t)bglob * T + t], po + (rb == 0 ? bl : 0.f));
        }

        // ---- group barrier (64 blocks): release h_{t+1}, acquire for t+1 ----
        __syncthreads();
        const unsigned int gen = (unsigned int)(t + 1);
        if (tid == 0) {
            __threadfence();
            __hip_atomic_store(&arrive[rb], gen, __ATOMIC_RELEASE, __HIP_MEMORY_SCOPE_AGENT);
        }
        if (rb == 0 && tid < 64) {
            while (__hip_atomic_load(&arrive[tid], __ATOMIC_ACQUIRE,
                                     __HIP_MEMORY_SCOPE_AGENT) < gen) {
                __builtin_amdgcn_s_sleep(1);
            }
            if (tid == 0) {
                __threadfence();
                __hip_atomic_store(release, gen, __ATOMIC_RELEASE, __HIP_MEMORY_SCOPE_AGENT);
            }
        }
        if (tid == 0) {
            while (__hip_atomic_load(release, __ATOMIC_ACQUIRE,
                                     __HIP_MEMORY_SCOPE_AGENT) < gen) {
                __builtin_amdgcn_s_sleep(1);
            }
        }
        __syncthreads();
    }
}

extern "C" void kernel_launch(void* const* d_in, const int* in_sizes, int n_in,
                              void* d_out, int out_size, void* d_ws, size_t ws_size,
                              hipStream_t stream) {
    const float* hidden0 = (const float*)d_in[0];
    const float* cell0   = (const float*)d_in[1];
    const float* Wih     = (const float*)d_in[2];
    const float* Whh     = (const float*)d_in[3];
    const float* bih     = (const float*)d_in[4];
    const float* bhh     = (const float*)d_in[5];
    const float* Wlin    = (const float*)d_in[6];
    const float* blin    = (const float*)d_in[7];
    float* out = (float*)d_out;
    float* ws  = (float*)d_ws;

    // zero the barrier flags and the atomically-accumulated output
    hipMemsetAsync(d_ws, 0, 4096, stream);
    hipMemsetAsync(d_out, 0, (size_t)B * T * sizeof(float), stream);

    void* args[] = { &hidden0, &cell0, &Wih, &Whh, &bih, &bhh, &Wlin, &blin,
                     &out, &ws };
    hipLaunchCooperativeKernel((const void*)decoder_kernel,
                               dim3(GROUPS * BPG), dim3(NTHR), args, 0, stream);
}

// Round 3
// 4559.572 us; speedup vs baseline: 3.4204x; 1.6219x over previous
//
#include <hip/hip_runtime.h>
#include <math.h>

#define H      1024
#define B      128
#define T      256
#define GROUPS 4
#define BPG    64        // blocks per group; block owns 16 hidden dims (64 gate rows)
#define NTHR   512
#define MPG    32        // batches per group
#define DPB    16        // dims per block
#define NCHUNK 64        // 32 kt x 2 mt fragment chunks of 1024 B
#define GRP_SHORTS (MPG * H)   // 32768 shorts = 64 KB per group per parity

#define AS1 __attribute__((address_space(1)))
#define AS3 __attribute__((address_space(3)))

typedef __attribute__((ext_vector_type(8))) short  bf16x8;
typedef __attribute__((ext_vector_type(4))) float  floatx4;

__device__ __forceinline__ unsigned short bf16_rne(float f) {
    unsigned int u = __float_as_uint(f);
    u += 0x7FFF + ((u >> 16) & 1);
    return (unsigned short)(u >> 16);
}
__device__ __forceinline__ float bf16_to_f(unsigned short h) {
    return __uint_as_float(((unsigned int)h) << 16);
}
__device__ __forceinline__ float sigmoidf_(float x) { return 1.0f / (1.0f + __expf(-x)); }

// h element (m, k) -> fragment-major short index:
// chunk c = kt*2 + mt (1024 B), slot = q*16 + (m&15), inner j = k&7.
__device__ __forceinline__ void store_h_frag(unsigned short* base, int m, int k, float v) {
    const int kt = k >> 5, q = (k >> 3) & 3, j = k & 7;
    const int c  = kt * 2 + (m >> 4);
    base[c * 512 + (q * 16 + (m & 15)) * 8 + j] = bf16_rne(v);
}

__device__ __forceinline__ void dma16(const void* g, void* l) {
    __builtin_amdgcn_global_load_lds((const AS1 void*)g, (AS3 void*)l, 16, 0, 0);
}

// Persistent LSTM decoder. 4 groups x 64 blocks; group g owns batches
// [32g, 32g+32). Block rb owns hidden dims [16rb, 16rb+16) => 64 gate rows.
// W' = W_hh + W_ih[:,0] (x) W_lin in registers as split hi/lo bf16 B-frags.
// h travels as bf16 (single plane) in fragment-major layout, written by the
// producer and DMA'd global->LDS by consumers. Counter barrier per group.
__global__ __launch_bounds__(NTHR, 2) void decoder_kernel(
    const float* __restrict__ hidden0, const float* __restrict__ cell0,
    const float* __restrict__ Wih,     const float* __restrict__ Whh,
    const float* __restrict__ bih,     const float* __restrict__ bhh,
    const float* __restrict__ Wlin,    const float* __restrict__ blin,
    float* __restrict__ out,           float* __restrict__ ws)
{
    __shared__ unsigned short planes[NCHUNK * 512];  // 64 KB staged h (bf16 frags)
    __shared__ float Dlds[4][2][32][18];             // 18 KB gate partials (pad 18: 2-way free)
    __shared__ float s0_lds[MPG];

    const int blk  = blockIdx.x;
    const int g    = blk >> 6;
    const int rb   = blk & 63;
    const int tid  = threadIdx.x;
    const int lane = tid & 63;
    const int wave = tid >> 6;          // 8 waves: (gate, kh)
    const int gate = wave & 3;
    const int kh   = wave >> 2;
    const int l15  = lane & 15;
    const int q    = lane >> 4;

    unsigned int*   ctr  = (unsigned int*)ws + g * 64;            // 256 B apart
    unsigned short* hbuf = (unsigned short*)((char*)ws + 4096);   // [2][GROUPS][GRP_SHORTS]

    // ---- W' B-fragments in registers (split hi/lo bf16) ----
    const int row = gate * H + rb * DPB + l15;
    bf16x8 w_hi[16], w_lo[16];
    {
        const float* wrow  = Whh + (size_t)row * H;
        const float  wih0r = Wih[row * 2];
        #pragma unroll
        for (int kt = 0; kt < 16; ++kt) {
            const int k0 = kh * 512 + kt * 32 + q * 8;
            #pragma unroll
            for (int j = 0; j < 8; ++j) {
                float w = wrow[k0 + j] + wih0r * Wlin[k0 + j];
                unsigned short hs = bf16_rne(w);
                float lo = w - bf16_to_f(hs);
                w_hi[kt][j] = (short)hs;
                w_lo[kt][j] = (short)bf16_rne(lo);
            }
        }
    }

    // ---- pointwise-thread constants: thread (pm, pj) ----
    const int pm    = tid >> 4;               // batch in group 0..31
    const int pj    = tid & 15;               // dim within block 0..15
    const int bglob = g * MPG + pm;
    const int kdim  = rb * DPB + pj;          // this thread's hidden dim
    const float bl  = blin[0];
    float bias_p[4], bias0_p[4], wih0_p[4];
    #pragma unroll
    for (int gt = 0; gt < 4; ++gt) {
        int r2 = gt * H + kdim;
        float b0 = bih[r2] + bhh[r2];
        float w0 = Wih[r2 * 2];
        bias0_p[gt] = b0;
        wih0_p[gt]  = w0;
        bias_p[gt]  = b0 + Wih[r2 * 2 + 1] + w0 * bl;   // folded bias (t>=1)
    }
    float cstate = cell0[(size_t)bglob * H + kdim];
    const float wlin_p = Wlin[kdim];

    // ---- s0[m] = Wlin . h0[m]  (t=0 rank-1 correction) ----
    {
        const float* hp = hidden0 + (size_t)bglob * H + pj * 64;
        const float* wp = Wlin + pj * 64;
        float s = 0.f;
        #pragma unroll 4
        for (int kk = 0; kk < 64; kk += 4) {
            float4 hv = *(const float4*)(hp + kk);
            float4 wv = *(const float4*)(wp + kk);
            s += hv.x * wv.x + hv.y * wv.y + hv.z * wv.z + hv.w * wv.w;
        }
        s += __shfl_xor(s, 1); s += __shfl_xor(s, 2);
        s += __shfl_xor(s, 4); s += __shfl_xor(s, 8);
        if (pj == 0) s0_lds[pm] = s;
    }

    // ---- preamble: convert hidden0 slice into hbuf parity 0 (frag layout) ----
    {
        unsigned short* dst = hbuf + (size_t)(0 * GROUPS + g) * GRP_SHORTS;
        float v = hidden0[(size_t)bglob * H + kdim];
        store_h_frag(dst, pm, kdim, v);
    }
    // group barrier: preamble writes visible (target 64)
    __syncthreads();
    if (tid == 0) {
        __threadfence();
        __hip_atomic_fetch_add(ctr, 1u, __ATOMIC_RELEASE, __HIP_MEMORY_SCOPE_AGENT);
        while (__hip_atomic_load(ctr, __ATOMIC_ACQUIRE, __HIP_MEMORY_SCOPE_AGENT) < 64u)
            __builtin_amdgcn_s_sleep(1);
    }
    __syncthreads();

    for (int t = 0; t < T; ++t) {
        // ---- async DMA: global frag buffer -> LDS (8 chunks of 1 KB per wave) ----
        const unsigned short* hsrc =
            hbuf + (size_t)((t & 1) * GROUPS + g) * GRP_SHORTS;
        #pragma unroll
        for (int i = 0; i < 8; ++i) {
            const int c = wave * 8 + i;
            dma16(hsrc + c * 512 + lane * 8, planes + c * 512);
        }
        __syncthreads();   // drains vmcnt (DMA) per wave + joins block

        // ---- MFMA: D[m][n] += h[m][k] W'[n][k], K-half kh ----
        floatx4 acc0 = {0.f, 0.f, 0.f, 0.f};
        floatx4 acc1 = {0.f, 0.f, 0.f, 0.f};
        #pragma unroll
        for (int kt16 = 0; kt16 < 16; ++kt16) {
            const int kt = kh * 16 + kt16;
            bf16x8 a0 = *(const bf16x8*)(planes + (kt * 2 + 0) * 512 + lane * 8);
            bf16x8 a1 = *(const bf16x8*)(planes + (kt * 2 + 1) * 512 + lane * 8);
            acc0 = __builtin_amdgcn_mfma_f32_16x16x32_bf16(a0, w_hi[kt16], acc0, 0, 0, 0);
            acc0 = __builtin_amdgcn_mfma_f32_16x16x32_bf16(a0, w_lo[kt16], acc0, 0, 0, 0);
            acc1 = __builtin_amdgcn_mfma_f32_16x16x32_bf16(a1, w_hi[kt16], acc1, 0, 0, 0);
            acc1 = __builtin_amdgcn_mfma_f32_16x16x32_bf16(a1, w_lo[kt16], acc1, 0, 0, 0);
        }
        #pragma unroll
        for (int r = 0; r < 4; ++r) {       // C/D: col=lane&15, row=q*4+r
            Dlds[gate][kh][q * 4 + r][l15]      = acc0[r];
            Dlds[gate][kh][16 + q * 4 + r][l15] = acc1[r];
        }
        __syncthreads();

        // ---- LSTM pointwise (thread = (pm, pj)) ----
        {
            float gi = Dlds[0][0][pm][pj] + Dlds[0][1][pm][pj];
            float gf = Dlds[1][0][pm][pj] + Dlds[1][1][pm][pj];
            float gg = Dlds[2][0][pm][pj] + Dlds[2][1][pm][pj];
            float go = Dlds[3][0][pm][pj] + Dlds[3][1][pm][pj];
            if (t == 0) {
                float s0 = s0_lds[pm];
                gi += bias0_p[0] - wih0_p[0] * s0;
                gf += bias0_p[1] - wih0_p[1] * s0;
                gg += bias0_p[2] - wih0_p[2] * s0;
                go += bias0_p[3] - wih0_p[3] * s0;
            } else {
                gi += bias_p[0]; gf += bias_p[1];
                gg += bias_p[2]; go += bias_p[3];
            }
            float ig  = sigmoidf_(gi);
            float fg  = sigmoidf_(gf);
            float gt_ = tanhf(gg);
            float og  = sigmoidf_(go);
            cstate = fg * cstate + ig * gt_;
            float hnew = og * tanhf(cstate);

            // producer-side bf16 fragment store for step t+1
            unsigned short* hdst =
                hbuf + (size_t)(((t + 1) & 1) * GROUPS + g) * GRP_SHORTS;
            store_h_frag(hdst, pm, kdim, hnew);

            // out[b][t] partial over this block's 16 dims
            float po = wlin_p * hnew;
            po += __shfl_xor(po, 1); po += __shfl_xor(po, 2);
            po += __shfl_xor(po, 4); po += __shfl_xor(po, 8);
            if (pj == 0)
                atomicAdd(&out[(size_t)bglob * T + t], po + (rb == 0 ? bl : 0.f));
        }

        // ---- group barrier (counter, target 64*(t+2)) ----
        __syncthreads();
        if (tid == 0) {
            const unsigned int target = 64u * (unsigned int)(t + 2);
            __threadfence();
            __hip_atomic_fetch_add(ctr, 1u, __ATOMIC_RELEASE, __HIP_MEMORY_SCOPE_AGENT);
            while (__hip_atomic_load(ctr, __ATOMIC_ACQUIRE, __HIP_MEMORY_SCOPE_AGENT) < target)
                __builtin_amdgcn_s_sleep(1);
        }
        __syncthreads();
    }
}

extern "C" void kernel_launch(void* const* d_in, const int* in_sizes, int n_in,
                              void* d_out, int out_size, void* d_ws, size_t ws_size,
                              hipStream_t stream) {
    const float* hidden0 = (const float*)d_in[0];
    const float* cell0   = (const float*)d_in[1];
    const float* Wih     = (const float*)d_in[2];
    const float* Whh     = (const float*)d_in[3];
    const float* bih     = (const float*)d_in[4];
    const float* bhh     = (const float*)d_in[5];
    const float* Wlin    = (const float*)d_in[6];
    const float* blin    = (const float*)d_in[7];
    float* out = (float*)d_out;
    float* ws  = (float*)d_ws;

    // zero barrier counters and atomically-accumulated output
    hipMemsetAsync(d_ws, 0, 4096, stream);
    hipMemsetAsync(d_out, 0, (size_t)B * T * sizeof(float), stream);

    void* args[] = { &hidden0, &cell0, &Wih, &Whh, &bih, &bhh, &Wlin, &blin,
                     &out, &ws };
    hipLaunchCooperativeKernel((const void*)decoder_kernel,
                               dim3(GROUPS * BPG), dim3(NTHR), args, 0, stream);
}

// Round 4
// 1865.830 us; speedup vs baseline: 8.3585x; 2.4437x over previous
//
#include <hip/hip_runtime.h>
#include <math.h>

#define H      1024
#define B      128
#define T      256
#define GROUPS 4
#define BPG    64        // blocks per group; block owns 16 hidden dims (64 gate rows)
#define NTHR   512
#define MPG    32        // batches per group
#define DPB    16        // dims per block
#define GRP_SHORTS (MPG * H)   // 32768 shorts = 64 KB per group per parity

#define AS1 __attribute__((address_space(1)))
#define AS3 __attribute__((address_space(3)))

typedef __attribute__((ext_vector_type(8))) short  bf16x8;
typedef __attribute__((ext_vector_type(4))) float  floatx4;
typedef __attribute__((ext_vector_type(4))) int    int4v;

static __device__ __forceinline__ unsigned short bf16_rne(float f) {
    unsigned int u = __float_as_uint(f);
    u += 0x7FFF + ((u >> 16) & 1);
    return (unsigned short)(u >> 16);
}
static __device__ __forceinline__ float bf16_to_f(unsigned short h) {
    return __uint_as_float(((unsigned int)h) << 16);
}
static __device__ __forceinline__ float sigmoidf_(float x) { return 1.0f / (1.0f + __expf(-x)); }

// h element (m, k) -> fragment-major short index (consumer DMA layout):
// chunk c = kt*2 + mt (1024 B), slot = q*16 + (m&15), inner j = k&7.
static __device__ __forceinline__ void store_h_frag(unsigned short* base, int m, int k, float v) {
    const int kt = k >> 5, q = (k >> 3) & 3, j = k & 7;
    const int c  = kt * 2 + (m >> 4);
    base[c * 512 + (q * 16 + (m & 15)) * 8 + j] = bf16_rne(v);
}

static __device__ __forceinline__ void dma16(const void* g, void* l) {
    __builtin_amdgcn_global_load_lds((const AS1 void*)g, (AS3 void*)l, 16, 0, 0);
}
// write-through stores: land at the device coherence point (L3), leave no
// dirty L2 line behind => no buffer_wbl2 ever needed in the loop.
static __device__ __forceinline__ void store16_wt(void* p, int4v v) {
    asm volatile("global_store_dwordx4 %0, %1, off sc0 sc1" :: "v"(p), "v"(v) : "memory");
}
static __device__ __forceinline__ void store4_wt(void* p, float v) {
    asm volatile("global_store_dword %0, %1, off sc0 sc1" :: "v"(p), "v"(v) : "memory");
}

// two-level group barrier, tid0 only. RELAXED arrives (no wbl2); caller's
// preceding __syncthreads drained the write-through stores; one ACQUIRE load
// at the end supplies the per-step buffer_inv (L1/L2 invalidate).
static __device__ __forceinline__ void group_barrier(unsigned int* subc, unsigned int* mainc,
                                                     int rb, unsigned int gen) {
    __hip_atomic_fetch_add(&subc[(rb & 7) * 32], 1u, __ATOMIC_RELAXED, __HIP_MEMORY_SCOPE_AGENT);
    if (rb < 8) {
        while (__hip_atomic_load(&subc[rb * 32], __ATOMIC_RELAXED, __HIP_MEMORY_SCOPE_AGENT) < 8u * gen)
            __builtin_amdgcn_s_sleep(1);
        __hip_atomic_fetch_add(mainc, 1u, __ATOMIC_RELAXED, __HIP_MEMORY_SCOPE_AGENT);
    }
    while (__hip_atomic_load(mainc, __ATOMIC_RELAXED, __HIP_MEMORY_SCOPE_AGENT) < 8u * gen)
        __builtin_amdgcn_s_sleep(1);
    (void)__hip_atomic_load(mainc, __ATOMIC_ACQUIRE, __HIP_MEMORY_SCOPE_AGENT);  // buffer_inv
}

// Persistent LSTM decoder. 4 groups x 64 blocks; group g owns batches
// [32g, 32g+32). Block rb owns hidden dims [16rb, 16rb+16) => 64 gate rows.
// W' = W_hh + W_ih[:,0] (x) W_lin in registers as split hi/lo bf16 B-frags.
// h travels bf16 fragment-major via write-through stores -> L3 -> DMA to LDS.
__global__ __launch_bounds__(NTHR, 2) void decoder_kernel(
    const float* __restrict__ hidden0, const float* __restrict__ cell0,
    const float* __restrict__ Wih,     const float* __restrict__ Whh,
    const float* __restrict__ bih,     const float* __restrict__ bhh,
    const float* __restrict__ Wlin,    const float* __restrict__ blin,
    float* __restrict__ out,           float* __restrict__ ws)
{
    __shared__ unsigned short planes[64 * 512];      // 64 KB staged h (bf16 frags)
    __shared__ float Dlds[4][2][32][18];             // 18 KB gate partials (pad 18)
    __shared__ float s0_lds[MPG];
    __shared__ __align__(16) unsigned short hstage[MPG * DPB];  // 1 KB bf16 h slice
    __shared__ float postage[MPG];                   // out-head partials

    const int blk  = blockIdx.x;
    const int g    = blk >> 6;
    const int rb   = blk & 63;
    const int tid  = threadIdx.x;
    const int lane = tid & 63;
    const int wave = tid >> 6;          // 8 waves: (gate, kh)
    const int gate = wave & 3;
    const int kh   = wave >> 2;
    const int l15  = lane & 15;
    const int q    = lane >> 4;

    // counters: sub_ctr[g][s] at (g*8+s)*32 uints (128 B apart), main at (32+g)*32
    unsigned int*   subc  = (unsigned int*)ws + g * 8 * 32;
    unsigned int*   mainc = (unsigned int*)ws + (32 + g) * 32;
    unsigned short* hbuf  = (unsigned short*)((char*)ws + 8192);            // [2][G][GRP_SHORTS]
    float*          pbuf  = (float*)((char*)ws + 8192 + 2 * GROUPS * GRP_SHORTS * 2); // [2][G][BPG][MPG]

    // ---- W' B-fragments in registers (split hi/lo bf16) ----
    const int row = gate * H + rb * DPB + l15;
    bf16x8 w_hi[16], w_lo[16];
    {
        const float* wrow  = Whh + (size_t)row * H;
        const float  wih0r = Wih[row * 2];
        #pragma unroll
        for (int kt = 0; kt < 16; ++kt) {
            const int k0 = kh * 512 + kt * 32 + q * 8;
            #pragma unroll
            for (int j = 0; j < 8; ++j) {
                float w = wrow[k0 + j] + wih0r * Wlin[k0 + j];
                unsigned short hs = bf16_rne(w);
                float lo = w - bf16_to_f(hs);
                w_hi[kt][j] = (short)hs;
                w_lo[kt][j] = (short)bf16_rne(lo);
            }
        }
    }

    // ---- pointwise-thread constants: thread (pm, pj) ----
    const int pm    = tid >> 4;               // batch in group 0..31
    const int pj    = tid & 15;               // dim within block 0..15
    const int bglob = g * MPG + pm;
    const int kdim  = rb * DPB + pj;
    const float bl  = blin[0];
    float bias_p[4], bias0_p[4], wih0_p[4];
    #pragma unroll
    for (int gt = 0; gt < 4; ++gt) {
        int r2 = gt * H + kdim;
        float b0 = bih[r2] + bhh[r2];
        float w0 = Wih[r2 * 2];
        bias0_p[gt] = b0;
        wih0_p[gt]  = w0;
        bias_p[gt]  = b0 + Wih[r2 * 2 + 1] + w0 * bl;   // folded bias (t>=1)
    }
    float cstate = cell0[(size_t)bglob * H + kdim];
    const float wlin_p = Wlin[kdim];

    // ---- s0[m] = Wlin . h0[m]  (t=0 rank-1 correction) ----
    {
        const float* hp = hidden0 + (size_t)bglob * H + pj * 64;
        const float* wp = Wlin + pj * 64;
        float s = 0.f;
        #pragma unroll 4
        for (int kk = 0; kk < 64; kk += 4) {
            float4 hv = *(const float4*)(hp + kk);
            float4 wv = *(const float4*)(wp + kk);
            s += hv.x * wv.x + hv.y * wv.y + hv.z * wv.z + hv.w * wv.w;
        }
        s += __shfl_xor(s, 1); s += __shfl_xor(s, 2);
        s += __shfl_xor(s, 4); s += __shfl_xor(s, 8);
        if (pj == 0) s0_lds[pm] = s;
    }

    // ---- preamble: h0 slice into hbuf parity 0 (plain stores + one-time fence) ----
    {
        unsigned short* dst = hbuf + (size_t)(0 * GROUPS + g) * GRP_SHORTS;
        store_h_frag(dst, pm, kdim, hidden0[(size_t)bglob * H + kdim]);
    }
    __threadfence();   // one-time wbl2: flush preamble plain stores to L3
    __syncthreads();
    if (tid == 0) group_barrier(subc, mainc, rb, 1u);
    __syncthreads();

    for (int t = 0; t < T; ++t) {
        // ---- phase A: DMA h_t -> LDS; wave1 reduces step t-1 output head ----
        const unsigned short* hsrc = hbuf + (size_t)((t & 1) * GROUPS + g) * GRP_SHORTS;
        #pragma unroll
        for (int i = 0; i < 8; ++i) {
            const int c = wave * 8 + i;
            dma16(hsrc + c * 512 + lane * 8, planes + c * 512);
        }
        if (wave == 1 && rb < MPG && t > 0) {
            // batch m = rb: sum 64 block-partials written at step t-1
            float v = pbuf[((size_t)(((t - 1) & 1) * GROUPS + g) * BPG + lane) * MPG + rb];
            v += __shfl_xor(v, 1);  v += __shfl_xor(v, 2);  v += __shfl_xor(v, 4);
            v += __shfl_xor(v, 8);  v += __shfl_xor(v, 16); v += __shfl_xor(v, 32);
            if (lane == 0) out[(size_t)(g * MPG + rb) * T + (t - 1)] = v + bl;
        }
        __syncthreads();   // per-wave vmcnt drain => DMA complete

        // ---- phase B: MFMA D[m][n] += h[m][k] W'[n][k], K-half kh ----
        floatx4 acc0 = {0.f, 0.f, 0.f, 0.f};
        floatx4 acc1 = {0.f, 0.f, 0.f, 0.f};
        #pragma unroll
        for (int kt16 = 0; kt16 < 16; ++kt16) {
            const int kt = kh * 16 + kt16;
            bf16x8 a0 = *(const bf16x8*)(planes + (kt * 2 + 0) * 512 + lane * 8);
            bf16x8 a1 = *(const bf16x8*)(planes + (kt * 2 + 1) * 512 + lane * 8);
            acc0 = __builtin_amdgcn_mfma_f32_16x16x32_bf16(a0, w_hi[kt16], acc0, 0, 0, 0);
            acc0 = __builtin_amdgcn_mfma_f32_16x16x32_bf16(a0, w_lo[kt16], acc0, 0, 0, 0);
            acc1 = __builtin_amdgcn_mfma_f32_16x16x32_bf16(a1, w_hi[kt16], acc1, 0, 0, 0);
            acc1 = __builtin_amdgcn_mfma_f32_16x16x32_bf16(a1, w_lo[kt16], acc1, 0, 0, 0);
        }
        #pragma unroll
        for (int r = 0; r < 4; ++r) {       // C/D: col=lane&15, row=q*4+r
            Dlds[gate][kh][q * 4 + r][l15]      = acc0[r];
            Dlds[gate][kh][16 + q * 4 + r][l15] = acc1[r];
        }
        __syncthreads();

        // ---- phase C: LSTM pointwise (thread = (pm, pj)) ----
        {
            float gi = Dlds[0][0][pm][pj] + Dlds[0][1][pm][pj];
            float gf = Dlds[1][0][pm][pj] + Dlds[1][1][pm][pj];
            float gg = Dlds[2][0][pm][pj] + Dlds[2][1][pm][pj];
            float go = Dlds[3][0][pm][pj] + Dlds[3][1][pm][pj];
            if (t == 0) {
                float s0 = s0_lds[pm];
                gi += bias0_p[0] - wih0_p[0] * s0;
                gf += bias0_p[1] - wih0_p[1] * s0;
                gg += bias0_p[2] - wih0_p[2] * s0;
                go += bias0_p[3] - wih0_p[3] * s0;
            } else {
                gi += bias_p[0]; gf += bias_p[1];
                gg += bias_p[2]; go += bias_p[3];
            }
            float ig  = sigmoidf_(gi);
            float fg  = sigmoidf_(gf);
            float gt_ = tanhf(gg);
            float og  = sigmoidf_(go);
            cstate = fg * cstate + ig * gt_;
            float hnew = og * tanhf(cstate);
            hstage[pm * DPB + pj] = bf16_rne(hnew);
            float po = wlin_p * hnew;
            po += __shfl_xor(po, 1); po += __shfl_xor(po, 2);
            po += __shfl_xor(po, 4); po += __shfl_xor(po, 8);
            if (pj == 0) postage[pm] = po;
        }
        __syncthreads();

        // ---- phase D: write-through stores (h slice 64x16B by wave0; pbuf by wave2) ----
        if (wave == 0) {
            const int m    = lane >> 1;
            const int half = lane & 1;
            const int qq   = (2 * rb + half) & 3;
            const int c    = (rb >> 1) * 2 + (m >> 4);
            unsigned short* hdst = hbuf + (size_t)(((t + 1) & 1) * GROUPS + g) * GRP_SHORTS
                                 + c * 512 + (qq * 16 + (m & 15)) * 8;
            int4v v = *(const int4v*)&hstage[m * DPB + half * 8];
            store16_wt(hdst, v);
        } else if (wave == 2 && lane < MPG) {
            float* pdst = pbuf + ((size_t)((t & 1) * GROUPS + g) * BPG + rb) * MPG + lane;
            store4_wt(pdst, postage[lane]);
        }
        __syncthreads();   // per-wave vmcnt(0) drains the wt stores before arrive

        // ---- phase E: group barrier ----
        if (tid == 0) group_barrier(subc, mainc, rb, (unsigned int)(t + 2));
        __syncthreads();
    }

    // ---- epilogue: output column t = T-1 ----
    if (wave == 1 && rb < MPG) {
        float v = pbuf[((size_t)(((T - 1) & 1) * GROUPS + g) * BPG + lane) * MPG + rb];
        v += __shfl_xor(v, 1);  v += __shfl_xor(v, 2);  v += __shfl_xor(v, 4);
        v += __shfl_xor(v, 8);  v += __shfl_xor(v, 16); v += __shfl_xor(v, 32);
        if (lane == 0) out[(size_t)(g * MPG + rb) * T + (T - 1)] = v + bl;
    }
}

extern "C" void kernel_launch(void* const* d_in, const int* in_sizes, int n_in,
                              void* d_out, int out_size, void* d_ws, size_t ws_size,
                              hipStream_t stream) {
    const float* hidden0 = (const float*)d_in[0];
    const float* cell0   = (const float*)d_in[1];
    const float* Wih     = (const float*)d_in[2];
    const float* Whh     = (const float*)d_in[3];
    const float* bih     = (const float*)d_in[4];
    const float* bhh     = (const float*)d_in[5];
    const float* Wlin    = (const float*)d_in[6];
    const float* blin    = (const float*)d_in[7];
    float* out = (float*)d_out;
    float* ws  = (float*)d_ws;

    // zero the barrier counters
    hipMemsetAsync(d_ws, 0, 8192, stream);

    void* args[] = { &hidden0, &cell0, &Wih, &Whh, &bih, &bhh, &Wlin, &blin,
                     &out, &ws };
    hipLaunchCooperativeKernel((const void*)decoder_kernel,
                               dim3(GROUPS * BPG), dim3(NTHR), args, 0, stream);
}